// Round 2
// 532.201 us; speedup vs baseline: 1.0213x; 1.0213x over previous
//
#include <hip/hip_runtime.h>
#include <cstddef>
#include <cstdint>

typedef short short8 __attribute__((ext_vector_type(8)));
typedef float floatx4 __attribute__((ext_vector_type(4)));

#define BATCH   32768
#define IN_DIM  1024
#define ROW_F   3072      // floats per x row (3*32*32)
#define EMBED   16
#define TINY    16
#define OUT     1000
#define NE      4
#define NT_N    63        // ceil(1000/16) column tiles
#define LSTR    104       // LDS hw-row stride in shorts (96 used + 8 pad)

#define BF_BYTES ((size_t)NT_N * 3 * 64 * 8 * 2)     // 193536

__device__ __forceinline__ unsigned short f2bf_rne(float f) {
    unsigned u = __builtin_bit_cast(unsigned, f);
    return (unsigned short)((u + 0x7FFFu + ((u >> 16) & 1u)) >> 16);
}

// ---------------------------------------------------------------------------
// Prep: pack Wcat[96x1000] (W2 rows, b2 rows, zero pad) into B-fragment order
// for 16x16x32 bf16 MFMA, and W_embed into hi/lo bf16 B-fragment order.
// B-frag element: lane holds B[k = s*32 + (lane>>4)*8 + i][n = ntile*16 + (lane&15)]
// ---------------------------------------------------------------------------
__global__ void k_prep(const float* __restrict__ W2, const float* __restrict__ b2,
                       const float* __restrict__ W_embed,
                       unsigned short* __restrict__ Bf,
                       unsigned short* __restrict__ WeF) {
    int tid = blockIdx.x * 256 + threadIdx.x;
    if (blockIdx.x < 48) {                  // Wcat fragments: 63*3*64 threads
        if (tid >= NT_N * 3 * 64) return;
        int n = tid / 192, r = tid % 192, s = r / 64, lane = r % 64;
        int col = n * 16 + (lane & 15);
        int kq = s * 32 + (lane >> 4) * 8;
        #pragma unroll
        for (int i = 0; i < 8; ++i) {
            int k = kq + i;
            float v = 0.f;
            if (col < OUT) {
                if (k < 64) v = W2[(size_t)((k >> 4) * 16 + (k & 15)) * OUT + col];
                else if (k < 68) v = b2[(size_t)(k - 64) * OUT + col];
            }
            Bf[(size_t)tid * 8 + i] = f2bf_rne(v);
        }
    } else {                                // W_embed hi/lo fragments: 32*64 threads
        int id = tid - 48 * 256;
        if (id >= 32 * 64) return;
        int s = id >> 6, lane = id & 63;
        int j = lane & 15;
        int kq = s * 32 + ((lane >> 4) << 3);
        #pragma unroll
        for (int i = 0; i < 8; ++i) {
            float w = W_embed[(size_t)j * IN_DIM + kq + i];
            unsigned u = __builtin_bit_cast(unsigned, w);
            WeF[id * 8 + i] = (unsigned short)(u >> 16);                 // hi (trunc)
            float hif = __builtin_bit_cast(float, u & 0xFFFF0000u);
            float d = w - hif;
            WeF[16384 + id * 8 + i] =
                (unsigned short)(__builtin_bit_cast(unsigned, d) >> 16); // lo
        }
    }
}

// ---------------------------------------------------------------------------
// Fused: per block (512 thr = 8 waves) handle 128 rows.
// Phase 1 (per wave, one 16-row tile): e = relu(x[:,:1024]@We^T+be) via
// hi/lo-split bf16 MFMA, gate = softmax(e@Wg^T+bg), h = relu(e@W1+b1);
// write hw rows (bf16, K=96: [0:64]=gate_i*h, [64:68]=gate, [68:96]=0) to LDS.
// Phase 2 (per wave, 8 column-tiles resident in 96 VGPRs): 16x1008 GEMM over
// the block's 8 m-subtiles, A-frags from LDS, store f32 out.
// ---------------------------------------------------------------------------
__global__ __launch_bounds__(512, 2) void k_fused(
    const float* __restrict__ x, const unsigned short* __restrict__ WeF,
    const float* __restrict__ b_embed, const float* __restrict__ W1,
    const float* __restrict__ b1, const float* __restrict__ Wg,
    const float* __restrict__ bg, const unsigned short* __restrict__ Bf,
    float* __restrict__ out)
{
    __shared__ float e_lds[8][16 * 20];     // per-wave e tile, row stride 20
    __shared__ float g_lds[8][64];          // per-wave gates: [i*16 + row]
    __shared__ __align__(16) short hwt[8][16][LSTR];  // hw tiles, 26.6 KB

    const int tid  = threadIdx.x;
    const int lane = tid & 63;
    const int wv   = tid >> 6;              // 0..7
    const int quad = lane >> 4;
    const int jcol = lane & 15;             // A: row-in-tile; C: embed index j
    const int row0 = (blockIdx.x * 8 + wv) * 16;

    // tiny weights into registers (used in the tail)
    const float be  = b_embed[jcol];
    const float bgr = bg[quad];             // gate phase: i = lane>>4
    float wgr[EMBED], w1r[EMBED];
    #pragma unroll
    for (int j = 0; j < EMBED; ++j) {
        wgr[j] = Wg[quad * EMBED + j];                         // Wg[i][j]
        w1r[j] = W1[(size_t)(quad * EMBED + j) * TINY + jcol]; // W1[i][j][t]
    }
    const float b1r = b1[lane];

    const short8* bhv = (const short8*)WeF;     // hi frags (global, L2-resident)
    const short8* blv = bhv + 2048;             // lo frags

    const float* xrow = x + (size_t)(row0 + jcol) * ROW_F + quad * 8;

    floatx4 acc0 = {0, 0, 0, 0}, acc1 = {0, 0, 0, 0};

    auto step = [&](float4 A0, float4 A1, short8 bh, short8 bl) {
        float fa[8] = {A0.x, A0.y, A0.z, A0.w, A1.x, A1.y, A1.z, A1.w};
        short8 ahi, alo;
        #pragma unroll
        for (int m = 0; m < 8; ++m) {
            unsigned u = __builtin_bit_cast(unsigned, fa[m]);
            ahi[m] = (short)(u >> 16);
            float hif = __builtin_bit_cast(float, u & 0xFFFF0000u);
            float d = fa[m] - hif;
            alo[m] = (short)(__builtin_bit_cast(unsigned, d) >> 16);
        }
        acc0 = __builtin_amdgcn_mfma_f32_16x16x32_bf16(ahi, bh, acc0, 0, 0, 0);
        acc1 = __builtin_amdgcn_mfma_f32_16x16x32_bf16(ahi, bl, acc1, 0, 0, 0);
        acc1 = __builtin_amdgcn_mfma_f32_16x16x32_bf16(alo, bh, acc1, 0, 0, 0);
    };

    // K-loop: 32 steps of K=32, software-pipelined one sp-iter (2 steps) ahead
    float4 c0, c1, c2, c3, n0, n1, n2, n3;
    short8 wh0 = bhv[lane],      wl0 = blv[lane];
    short8 wh1 = bhv[64 + lane], wl1 = blv[64 + lane];
    c0 = *(const float4*)(xrow + 0);
    c1 = *(const float4*)(xrow + 4);
    c2 = *(const float4*)(xrow + 32);
    c3 = *(const float4*)(xrow + 36);
    #pragma unroll
    for (int sp = 0; sp < 16; ++sp) {
        short8 nh0 = wh0, nl0 = wl0, nh1 = wh1, nl1 = wl1;
        if (sp < 15) {
            const float* p = xrow + (sp * 2 + 2) * 32;
            n0 = *(const float4*)(p + 0);
            n1 = *(const float4*)(p + 4);
            n2 = *(const float4*)(p + 32);
            n3 = *(const float4*)(p + 36);
            nh0 = bhv[(2 * sp + 2) * 64 + lane];
            nl0 = blv[(2 * sp + 2) * 64 + lane];
            nh1 = bhv[(2 * sp + 3) * 64 + lane];
            nl1 = blv[(2 * sp + 3) * 64 + lane];
        }
        step(c0, c1, wh0, wl0);
        step(c2, c3, wh1, wl1);
        c0 = n0; c1 = n1; c2 = n2; c3 = n3;
        wh0 = nh0; wl0 = nl0; wh1 = nh1; wl1 = nl1;
    }

    // e tile -> LDS. C layout: col(j) = lane&15, row = quad*4 + reg
    float* el = e_lds[wv];
    #pragma unroll
    for (int reg = 0; reg < 4; ++reg) {
        float e = fmaxf(acc0[reg] + acc1[reg] + be, 0.f);
        el[(quad * 4 + reg) * 20 + jcol] = e;
    }
    __syncthreads();

    // gate phase: lane -> (row = lane&15, i = lane>>4)
    {
        const int grow = lane & 15;
        float logit = bgr;
        #pragma unroll
        for (int j = 0; j < EMBED; ++j)
            logit = fmaf(el[grow * 20 + j], wgr[j], logit);
        float mx = fmaxf(logit, __shfl_xor(logit, 16));
        mx = fmaxf(mx, __shfl_xor(mx, 32));
        float ex = __expf(logit - mx);
        float sm = ex + __shfl_xor(ex, 16);
        sm = sm + __shfl_xor(sm, 32);
        g_lds[wv][lane] = ex / sm;          // g_lds[i*16 + row]
    }
    __syncthreads();

    // h phase: lane -> (i = lane>>4, t = lane&15); write hw rows into LDS
    #pragma unroll
    for (int r = 0; r < 16; ++r) {
        const float4* ev = (const float4*)(el + r * 20);
        float4 e0 = ev[0], e1 = ev[1], e2 = ev[2], e3 = ev[3];
        float h = b1r;
        h = fmaf(e0.x, w1r[0],  h); h = fmaf(e0.y, w1r[1],  h);
        h = fmaf(e0.z, w1r[2],  h); h = fmaf(e0.w, w1r[3],  h);
        h = fmaf(e1.x, w1r[4],  h); h = fmaf(e1.y, w1r[5],  h);
        h = fmaf(e1.z, w1r[6],  h); h = fmaf(e1.w, w1r[7],  h);
        h = fmaf(e2.x, w1r[8],  h); h = fmaf(e2.y, w1r[9],  h);
        h = fmaf(e2.z, w1r[10], h); h = fmaf(e2.w, w1r[11], h);
        h = fmaf(e3.x, w1r[12], h); h = fmaf(e3.y, w1r[13], h);
        h = fmaf(e3.z, w1r[14], h); h = fmaf(e3.w, w1r[15], h);
        h = fmaxf(h, 0.f);
        const float gate = g_lds[wv][quad * 16 + r];
        short* orow = hwt[wv][r];
        orow[lane] = (short)f2bf_rne(gate * h);
        if (lane < 4)        orow[64 + lane] = (short)f2bf_rne(g_lds[wv][lane * 16 + r]);
        else if (lane < 32)  orow[64 + lane] = 0;   // zero pad k=68..95
    }

    // ---- phase 2: out tiles. Wave owns 8 column-tiles (B in 96 VGPRs). ----
    const int nt0 = wv * 8;
    const int NT  = (wv == 7) ? 7 : 8;      // 63 n-tiles over 8 waves
    const int cl  = lane & 15;
    const short8* bfv = (const short8*)Bf;

    short8 bfrag[8][3];                     // issued before the barrier: in
    #pragma unroll                          // flight while waves drain phase 1
    for (int nt = 0; nt < 8; ++nt)
        if (nt < NT)
            #pragma unroll
            for (int s = 0; s < 3; ++s)
                bfrag[nt][s] = bfv[(size_t)((nt0 + nt) * 3 + s) * 64 + lane];

    __syncthreads();                        // hwt of all 8 waves visible

    for (int mt = 0; mt < 8; ++mt) {
        const short* arow = hwt[mt][cl];    // A-frag: row=cl, k=s*32+quad*8+i
        short8 a0 = *(const short8*)(arow + (0 * 4 + quad) * 8);
        short8 a1 = *(const short8*)(arow + (1 * 4 + quad) * 8);
        short8 a2 = *(const short8*)(arow + (2 * 4 + quad) * 8);

        floatx4 acc[8];
        #pragma unroll
        for (int nt = 0; nt < 8; ++nt) acc[nt] = (floatx4){0, 0, 0, 0};

        #pragma unroll
        for (int nt = 0; nt < 8; ++nt)
            if (nt < NT)
                acc[nt] = __builtin_amdgcn_mfma_f32_16x16x32_bf16(a0, bfrag[nt][0], acc[nt], 0, 0, 0);
        #pragma unroll
        for (int nt = 0; nt < 8; ++nt)
            if (nt < NT)
                acc[nt] = __builtin_amdgcn_mfma_f32_16x16x32_bf16(a1, bfrag[nt][1], acc[nt], 0, 0, 0);
        #pragma unroll
        for (int nt = 0; nt < 8; ++nt)
            if (nt < NT)
                acc[nt] = __builtin_amdgcn_mfma_f32_16x16x32_bf16(a2, bfrag[nt][2], acc[nt], 0, 0, 0);

        const int rowb = (blockIdx.x * 8 + mt) * 16 + quad * 4;
        #pragma unroll
        for (int nt = 0; nt < 8; ++nt) {
            if (nt < NT) {
                const int col = (nt0 + nt) * 16 + cl;
                if (col < OUT) {
                    #pragma unroll
                    for (int reg = 0; reg < 4; ++reg)
                        out[(size_t)(rowb + reg) * OUT + col] = acc[nt][reg];
                }
            }
        }
    }
}

extern "C" void kernel_launch(void* const* d_in, const int* in_sizes, int n_in,
                              void* d_out, int out_size, void* d_ws, size_t ws_size,
                              hipStream_t stream) {
    const float* x       = (const float*)d_in[0];
    const float* W_embed = (const float*)d_in[1];
    const float* b_embed = (const float*)d_in[2];
    const float* W1      = (const float*)d_in[3];
    const float* b1      = (const float*)d_in[4];
    const float* W2      = (const float*)d_in[5];
    const float* b2      = (const float*)d_in[6];
    const float* Wg      = (const float*)d_in[7];
    const float* bg      = (const float*)d_in[8];
    float* out = (float*)d_out;

    unsigned short* Bf  = (unsigned short*)d_ws;
    unsigned short* WeF = (unsigned short*)((char*)d_ws + BF_BYTES);

    k_prep<<<56, 256, 0, stream>>>(W2, b2, W_embed, Bf, WeF);
    k_fused<<<256, 512, 0, stream>>>(x, WeF, b_embed, W1, b1, Wg, bg, Bf, out);
}